// Round 1
// baseline (184.709 us; speedup 1.0000x reference)
//
#include <hip/hip_runtime.h>
#include <math.h>

#define B_ 8
#define N_ 2048
#define C_ 512
#define K_ 8
#define EPS 1e-6f
#define GENO_RATIO 0.1f

typedef __bf16 bf16x8 __attribute__((ext_vector_type(8)));
typedef float f32x4 __attribute__((ext_vector_type(4)));
typedef unsigned int u32;

__device__ __forceinline__ ushort f2bf(float x) {
    unsigned int u = __float_as_uint(x);
    u += 0x7fffu + ((u >> 16) & 1u);   // RNE (inputs are finite)
    return (ushort)(u >> 16);
}

__device__ __forceinline__ bf16x8 as_bf(uint4 x) {
    union { uint4 u; bf16x8 b; } t; t.u = x; return t.b;
}

// async global->LDS, 16B per lane. lds ptr must be wave-uniform (base+lane*16).
__device__ __forceinline__ void a_issue16(const ushort* g, ushort* l) {
    __builtin_amdgcn_global_load_lds(
        (const __attribute__((address_space(1))) u32*)g,
        (__attribute__((address_space(3))) u32*)l, 16, 0, 0);
}

// ---------------------------------------------------------------------------
// ws layout (float element offsets):
// [64,2112)            cnt (int)   [B,K] padded stride 32 (1 line/counter)
// [2112,4160)          mass        [B,K] padded stride 32
// [4160,36928)         hsum        [B,K,C]
// [36928,168000)       lw          [B,K,N]
// [168000,299072)      ln (int)    [B,K,N]
// [299072,1347648)     w1t2 (bf16) [K][16 cb][512 n][32 cc]   4 MB
// [1347648,5541952)    tb2  (bf16) [B][16 cb][2048 n][32 cc]  16.8 MB
// cnt/mass/hsum zeroed by hipMemsetAsync before k_prep.
// ---------------------------------------------------------------------------

// fused: gating (+geno, + bf16 K-tiled token copy, + direct list build via
// padded global atomics) for blocks [0,4096); w1 transpose for [4096,4608).
__global__ __launch_bounds__(256) void k_prep(const float* __restrict__ tokens,
                                              const float* __restrict__ gate_w,
                                              const float* __restrict__ gate_b,
                                              const float* __restrict__ geno_vec,
                                              const float* __restrict__ geno_w,
                                              const float* __restrict__ geno_b,
                                              const float* __restrict__ w1,
                                              int* __restrict__ cnt,
                                              float* __restrict__ mass,
                                              int* __restrict__ ln,
                                              float* __restrict__ lw,
                                              ushort* __restrict__ tb2,
                                              ushort* __restrict__ w1t2) {
    __shared__ float smem[8192];   // 32 KB, shared by both bodies
    int tid = threadIdx.x;
    if (blockIdx.x < 4096) {
        float* gwT = smem;          // [8][512] gate_w transposed
        float* qwT = smem + 4096;   // [8][512] geno_w transposed
        for (int i = tid; i < 1024; i += 256) {
            int c = i >> 1, j0 = (i & 1) * 4;
            float4 v = *(const float4*)(gate_w + i * 4);
            gwT[(j0 + 0) * 512 + c] = v.x; gwT[(j0 + 1) * 512 + c] = v.y;
            gwT[(j0 + 2) * 512 + c] = v.z; gwT[(j0 + 3) * 512 + c] = v.w;
            float4 u = *(const float4*)(geno_w + i * 4);
            qwT[(j0 + 0) * 512 + c] = u.x; qwT[(j0 + 1) * 512 + c] = u.y;
            qwT[(j0 + 2) * 512 + c] = u.z; qwT[(j0 + 3) * 512 + c] = u.w;
        }
        __syncthreads();

        int wave = tid >> 6, lane = tid & 63;
        int t = blockIdx.x * 4 + wave;
        int b = t >> 11;
        int n = t & 2047;
        int c0 = lane * 8;
        const float* trow = tokens + (size_t)t * C_;
        float4 v0 = *(const float4*)(trow + c0);
        float4 v1 = *(const float4*)(trow + c0 + 4);
        const float* grow = geno_vec + (size_t)b * C_;
        float4 gy0 = *(const float4*)(grow + c0);
        float4 gy1 = *(const float4*)(grow + c0 + 4);
        float tv[8] = {v0.x, v0.y, v0.z, v0.w, v1.x, v1.y, v1.z, v1.w};
        float gv[8] = {gy0.x, gy0.y, gy0.z, gy0.w, gy1.x, gy1.y, gy1.z, gy1.w};

        float acc[8];
        #pragma unroll
        for (int j = 0; j < 8; ++j) {
            const float* wj = gwT + j * 512 + c0;
            const float* qj = qwT + j * 512 + c0;
            float4 w0 = *(const float4*)(wj);
            float4 w1v = *(const float4*)(wj + 4);
            float4 q0 = *(const float4*)(qj);
            float4 q1 = *(const float4*)(qj + 4);
            float a = 0.f, g = 0.f;
            a = fmaf(tv[0], w0.x, a); a = fmaf(tv[1], w0.y, a);
            a = fmaf(tv[2], w0.z, a); a = fmaf(tv[3], w0.w, a);
            a = fmaf(tv[4], w1v.x, a); a = fmaf(tv[5], w1v.y, a);
            a = fmaf(tv[6], w1v.z, a); a = fmaf(tv[7], w1v.w, a);
            g = fmaf(gv[0], q0.x, g); g = fmaf(gv[1], q0.y, g);
            g = fmaf(gv[2], q0.z, g); g = fmaf(gv[3], q0.w, g);
            g = fmaf(gv[4], q1.x, g); g = fmaf(gv[5], q1.y, g);
            g = fmaf(gv[6], q1.z, g); g = fmaf(gv[7], q1.w, g);
            acc[j] = fmaf(GENO_RATIO, g, a);
        }
        {
            int cb = c0 >> 5, cc = c0 & 31;
            uint4 o;
            o.x = (unsigned)f2bf(tv[0]) | ((unsigned)f2bf(tv[1]) << 16);
            o.y = (unsigned)f2bf(tv[2]) | ((unsigned)f2bf(tv[3]) << 16);
            o.z = (unsigned)f2bf(tv[4]) | ((unsigned)f2bf(tv[5]) << 16);
            o.w = (unsigned)f2bf(tv[6]) | ((unsigned)f2bf(tv[7]) << 16);
            *(uint4*)(tb2 + ((size_t)(b * 16 + cb) * 2048 + n) * 32 + cc) = o;
        }
        #pragma unroll
        for (int off = 32; off > 0; off >>= 1) {
            #pragma unroll
            for (int j = 0; j < 8; ++j) acc[j] += __shfl_xor(acc[j], off, 64);
        }
        if (lane == 0) {
            float lg[8];
            #pragma unroll
            for (int j = 0; j < 8; ++j)
                lg[j] = acc[j] + gate_b[j] + GENO_RATIO * geno_b[j];
            int i0 = 0; float v0m = lg[0];
            #pragma unroll
            for (int j = 1; j < 8; ++j) if (lg[j] > v0m) { v0m = lg[j]; i0 = j; }
            int i1 = -1; float v1m = -1e30f;
            #pragma unroll
            for (int j = 0; j < 8; ++j) if (j != i0 && lg[j] > v1m) { v1m = lg[j]; i1 = j; }
            float e = expf(v1m - v0m);
            float w0 = 1.f / (1.f + e);
            float w1s = e / (1.f + e);
            w0 = fmaxf(w0, EPS); w1s = fmaxf(w1s, EPS);
            float s = w0 + w1s; w0 /= s; w1s /= s;
            // direct list build: order-insensitive (ffn1 gathers, hsum atomic)
            int p0 = b * 8 + i0, p1 = b * 8 + i1;
            int pos0 = atomicAdd(cnt + (p0 << 5), 1);
            int pos1 = atomicAdd(cnt + (p1 << 5), 1);
            ln[p0 * N_ + pos0] = n;  lw[p0 * N_ + pos0] = w0;
            ln[p1 * N_ + pos1] = n;  lw[p1 * N_ + pos1] = w1s;
            atomicAdd(mass + (p0 << 5), w0);
            atomicAdd(mass + (p1 << 5), w1s);
        }
    } else {
        // w1 transpose+convert: w1t2[k][cb][n][cc] = bf16(w1[k][cb*32+cc][n])
        int id2 = blockIdx.x - 4096;
        int k = id2 >> 6;
        int c0 = ((id2 >> 3) & 7) * 64;
        int n0 = (id2 & 7) * 64;
        float (*tile)[65] = (float(*)[65])smem;
        int tr = tid >> 4;          // 0..15
        int tc4 = (tid & 15) * 4;   // 0..60
        const float* src = w1 + (size_t)k * C_ * C_;
        #pragma unroll
        for (int i = 0; i < 4; ++i) {
            int c = c0 + tr + i * 16;
            float4 v = *(const float4*)(src + (size_t)c * C_ + n0 + tc4);
            tile[tr + i * 16][tc4 + 0] = v.x; tile[tr + i * 16][tc4 + 1] = v.y;
            tile[tr + i * 16][tc4 + 2] = v.z; tile[tr + i * 16][tc4 + 3] = v.w;
        }
        __syncthreads();
        #pragma unroll
        for (int i = 0; i < 4; ++i) {
            int rr = tr + i * 16;
            int n = n0 + rr;
            int c = c0 + tc4;
            int cb = c >> 5, cc = c & 31;
            uint2 o;
            o.x = (unsigned)f2bf(tile[tc4 + 0][rr]) | ((unsigned)f2bf(tile[tc4 + 1][rr]) << 16);
            o.y = (unsigned)f2bf(tile[tc4 + 2][rr]) | ((unsigned)f2bf(tile[tc4 + 3][rr]) << 16);
            *(uint2*)(w1t2 + ((size_t)(k * 16 + cb) * 512 + n) * 32 + cc) = o;
        }
    }
}

// grouped GEMM1, MFMA bf16. id = k + 8*b + 64*m  -> id&7 = k = XCD so each
// XCD keeps one expert's w1t2 (512 KB) hot in its private L2.
// Pipeline: A via global_load_lds into 3-slot LDS ring (2-deep), B 2-deep in
// VGPRs, raw s_barrier + counted s_waitcnt vmcnt(9) (never 0 in main loop).
__global__ __launch_bounds__(256, 2) void k_ffn1(const ushort* __restrict__ tb2,
                                                 const ushort* __restrict__ w1t2,
                                                 const float* __restrict__ b1,
                                                 const int* __restrict__ cnt,
                                                 const int* __restrict__ ln,
                                                 const float* __restrict__ lw,
                                                 float* __restrict__ hsum) {
    int id = blockIdx.x;
    int k = id & 7, b = (id >> 3) & 7, m = id >> 6;
    int p = b * 8 + k;
    int count = cnt[p << 5];
    int m0 = m * 64;
    if (m0 >= count) return;

    __shared__ __align__(16) ushort As[3][2048];   // 3 slots x 64 rows x 32 cc
    __shared__ int   ns_s[64];
    __shared__ float wls_s[64];
    int tid = threadIdx.x;
    if (tid < 64) {
        int mi = m0 + tid;
        bool v = mi < count;
        ns_s[tid]  = v ? ln[p * N_ + mi] : 0;
        wls_s[tid] = v ? lw[p * N_ + mi] : 0.f;
    }
    __syncthreads();

    int wv = tid >> 6, lane = tid & 63;
    int ln15 = lane & 15, q = lane >> 4;
    int r = tid >> 2, q4 = tid & 3;
    // gload_lds: wave-uniform LDS base (slot + wv*1024B); lane lands at +lane*16B
    // = byte tid*16 = row (tid>>2)*64 + piece (tid&3)*16 -> linear [64][32] tile.
    const ushort* ag = tb2 + ((size_t)(b * 16) * 2048 + ns_s[r]) * 32 + q4 * 8;
    const ushort* bb = w1t2 + ((size_t)(k * 16) * 512 + wv * 128 + ln15) * 32 + q * 8;

    f32x4 acc[4][8];
    #pragma unroll
    for (int mt = 0; mt < 4; ++mt)
        #pragma unroll
        for (int j = 0; j < 8; ++j) acc[mt][j] = (f32x4){0.f, 0.f, 0.f, 0.f};

    uint4 bA[8], bB[8];
    const ushort* s0 = &As[0][0];
    const ushort* s1 = &As[1][0];
    const ushort* s2 = &As[2][0];

    // prologue: issue stages 0 and 1 (9 VMEM ops each: 1 gload_lds + 8 b-loads)
    a_issue16(ag, (ushort*)s0 + wv * 512);
    #pragma unroll
    for (int j = 0; j < 8; ++j) bA[j] = *(const uint4*)(bb + j * 512);
    a_issue16(ag + 65536, (ushort*)s1 + wv * 512);
    #pragma unroll
    for (int j = 0; j < 8; ++j) bB[j] = *(const uint4*)(bb + 16384 + j * 512);

    #pragma unroll 1
    for (int cb = 0; cb < 14; cb += 2) {
        {   // body cb (even): read s0, consume bA, issue stage cb+2 -> s2/bA
            asm volatile("s_waitcnt vmcnt(9)" ::: "memory");
            __builtin_amdgcn_s_barrier();
            __builtin_amdgcn_sched_barrier(0);
            bf16x8 af[4];
            #pragma unroll
            for (int mt = 0; mt < 4; ++mt)
                af[mt] = *(const bf16x8*)(s0 + (mt * 16 + ln15) * 32 + q * 8);
            a_issue16(ag + (size_t)(cb + 2) * 65536, (ushort*)s2 + wv * 512);
            #pragma unroll
            for (int mt = 0; mt < 4; ++mt)
                #pragma unroll
                for (int j = 0; j < 8; ++j)
                    acc[mt][j] = __builtin_amdgcn_mfma_f32_16x16x32_bf16(
                        af[mt], as_bf(bA[j]), acc[mt][j], 0, 0, 0);
            #pragma unroll
            for (int j = 0; j < 8; ++j)
                bA[j] = *(const uint4*)(bb + (size_t)(cb + 2) * 16384 + j * 512);
        }
        {   // body cb+1 (odd): read s1, consume bB, issue stage cb+3 -> s0/bB
            asm volatile("s_waitcnt vmcnt(9)" ::: "memory");
            __builtin_amdgcn_s_barrier();
            __builtin_amdgcn_sched_barrier(0);
            bf16x8 af[4];
            #pragma unroll
            for (int mt = 0; mt < 4; ++mt)
                af[mt] = *(const bf16x8*)(s1 + (mt * 16 + ln15) * 32 + q * 8);
            a_issue16(ag + (size_t)(cb + 3) * 65536, (ushort*)s0 + wv * 512);
            #pragma unroll
            for (int mt = 0; mt < 4; ++mt)
                #pragma unroll
                for (int j = 0; j < 8; ++j)
                    acc[mt][j] = __builtin_amdgcn_mfma_f32_16x16x32_bf16(
                        af[mt], as_bf(bB[j]), acc[mt][j], 0, 0, 0);
            #pragma unroll
            for (int j = 0; j < 8; ++j)
                bB[j] = *(const uint4*)(bb + (size_t)(cb + 3) * 16384 + j * 512);
        }
        const ushort* t = s2; s2 = s1; s1 = s0; s0 = t;
    }
    {   // body 14: read s0 (slot 2), consume bA; A15/B15 (9 ops) stay in flight
        asm volatile("s_waitcnt vmcnt(9)" ::: "memory");
        __builtin_amdgcn_s_barrier();
        __builtin_amdgcn_sched_barrier(0);
        bf16x8 af[4];
        #pragma unroll
        for (int mt = 0; mt < 4; ++mt)
            af[mt] = *(const bf16x8*)(s0 + (mt * 16 + ln15) * 32 + q * 8);
        #pragma unroll
        for (int mt = 0; mt < 4; ++mt)
            #pragma unroll
            for (int j = 0; j < 8; ++j)
                acc[mt][j] = __builtin_amdgcn_mfma_f32_16x16x32_bf16(
                    af[mt], as_bf(bA[j]), acc[mt][j], 0, 0, 0);
    }
    {   // body 15: final drain
        asm volatile("s_waitcnt vmcnt(0)" ::: "memory");
        __builtin_amdgcn_s_barrier();
        __builtin_amdgcn_sched_barrier(0);
        bf16x8 af[4];
        #pragma unroll
        for (int mt = 0; mt < 4; ++mt)
            af[mt] = *(const bf16x8*)(s1 + (mt * 16 + ln15) * 32 + q * 8);
        #pragma unroll
        for (int mt = 0; mt < 4; ++mt)
            #pragma unroll
            for (int j = 0; j < 8; ++j)
                acc[mt][j] = __builtin_amdgcn_mfma_f32_16x16x32_bf16(
                    af[mt], as_bf(bB[j]), acc[mt][j], 0, 0, 0);
    }

    // epilogue: bias+relu+gate-weight; reduce 4 q-lanes; 1 atomic per column
    float wrow[4][4];
    #pragma unroll
    for (int mt = 0; mt < 4; ++mt)
        #pragma unroll
        for (int rr = 0; rr < 4; ++rr) wrow[mt][rr] = wls_s[mt * 16 + q * 4 + rr];
    const float* b1k = b1 + k * C_;
    float* hp = hsum + (size_t)p * C_;
    #pragma unroll
    for (int j = 0; j < 8; ++j) {
        int n = wv * 128 + j * 16 + ln15;
        float bias = b1k[n];
        float s = 0.f;
        #pragma unroll
        for (int mt = 0; mt < 4; ++mt)
            #pragma unroll
            for (int rr = 0; rr < 4; ++rr)
                s += wrow[mt][rr] * fmaxf(acc[mt][j][rr] + bias, 0.f);
        s += __shfl_xor(s, 16, 64);
        s += __shfl_xor(s, 32, 64);
        if (q == 0) atomicAdd(&hp[n], s);
    }
}

// fused combine+finalize: out[b,k,e] = (hsum[b,k,:]@w2[k,:,e] + b2*mass)/max(mass,eps)
// grid (et=8, k=8). Block stages hsum for all 8 b (16 KB), 4 waves split c.
__global__ __launch_bounds__(256) void k_comb(const float* __restrict__ hsum,
                                              const float* __restrict__ w2,
                                              const float* __restrict__ b2,
                                              const float* __restrict__ mass,
                                              const int* __restrict__ cnt,
                                              float* __restrict__ out) {
    int et = blockIdx.x, k = blockIdx.y;
    int e0 = et * 64;
    __shared__ float hs[8][512];
    __shared__ float racc[4][8][64];
    int tid = threadIdx.x;
    for (int i = tid; i < 1024; i += 256) {
        int bb = i >> 7, c4 = (i & 127) << 2;
        *(float4*)&hs[bb][c4] = *(const float4*)(hsum + ((size_t)(bb * 8 + k) << 9) + c4);
    }
    __syncthreads();
    int g = tid >> 6, lane = tid & 63;
    const float* w2p = w2 + (size_t)k * (C_ * C_) + e0 + lane;
    float a[8] = {0.f, 0.f, 0.f, 0.f, 0.f, 0.f, 0.f, 0.f};
    #pragma unroll 4
    for (int c = g; c < 512; c += 4) {
        float wvv = w2p[(size_t)c << 9];
        #pragma unroll
        for (int bb = 0; bb < 8; ++bb) a[bb] = fmaf(hs[bb][c], wvv, a[bb]);
    }
    #pragma unroll
    for (int bb = 0; bb < 8; ++bb) racc[g][bb][lane] = a[bb];
    __syncthreads();
    for (int i = tid; i < 512; i += 256) {
        int bb = i >> 6, le = i & 63;
        float s = racc[0][bb][le] + racc[1][bb][le] + racc[2][bb][le] + racc[3][bb][le];
        float mm = mass[(bb * 8 + k) << 5];
        out[((size_t)(bb * 8 + k) << 9) + e0 + le] =
            (s + b2[k * C_ + e0 + le] * mm) / fmaxf(mm, EPS);
    }
    if (et == 0 && k == 0 && tid == 0) {
        float u[8]; float ssum = 0.f;
        for (int kk = 0; kk < 8; ++kk) {
            int ck = 0;
            for (int bb2 = 0; bb2 < 8; ++bb2) ck += cnt[(bb2 * 8 + kk) << 5];
            u[kk] = (float)ck / (float)(B_ * N_);
            ssum += u[kk];
        }
        float mean = ssum / 8.f;
        float var = 0.f;
        for (int kk = 0; kk < 8; ++kk) { float d = u[kk] - mean; var += d * d; }
        var /= 8.f;
        float denom = mean + EPS;
        out[B_ * K_ * C_] = var / (denom * denom);
    }
}

extern "C" void kernel_launch(void* const* d_in, const int* in_sizes, int n_in,
                              void* d_out, int out_size, void* d_ws, size_t ws_size,
                              hipStream_t stream) {
    (void)in_sizes; (void)n_in; (void)out_size; (void)ws_size;
    const float* tokens   = (const float*)d_in[0];
    const float* geno_vec = (const float*)d_in[1];
    const float* gate_w   = (const float*)d_in[2];
    const float* gate_b   = (const float*)d_in[3];
    const float* geno_w   = (const float*)d_in[4];
    const float* geno_b   = (const float*)d_in[5];
    const float* w1       = (const float*)d_in[6];
    const float* b1       = (const float*)d_in[7];
    const float* w2       = (const float*)d_in[8];
    const float* b2       = (const float*)d_in[9];
    float* out = (float*)d_out;
    float* ws  = (float*)d_ws;

    int*    cnt  = (int*)(ws + 64);            // padded [64][32]
    float*  mass = ws + 2112;                  // padded [64][32]
    float*  hsum = ws + 4160;                  // [64][512]
    float*  lw   = ws + 36928;                 // [64][2048]
    int*    ln   = (int*)(ws + 168000);        // [64][2048]
    ushort* w1t2 = (ushort*)(ws + 299072);     // 4 MB bf16
    ushort* tb2  = (ushort*)(ws + 1347648);    // 16.8 MB bf16

    hipMemsetAsync(ws + 64, 0, (size_t)(36928 - 64) * sizeof(float), stream);
    k_prep<<<dim3(4096 + 512), dim3(256), 0, stream>>>(tokens, gate_w, gate_b,
                                                       geno_vec, geno_w, geno_b,
                                                       w1, cnt, mass, ln, lw,
                                                       tb2, w1t2);
    k_ffn1<<<dim3(B_ * K_ * (N_ / 64)), dim3(256), 0, stream>>>(tb2, w1t2, b1,
                                                                cnt, ln, lw, hsum);
    k_comb<<<dim3(8, K_), dim3(256), 0, stream>>>(hsum, w2, b2, mass, cnt, out);
}

// Round 2
// 168.352 us; speedup vs baseline: 1.0972x; 1.0972x over previous
//
#include <hip/hip_runtime.h>
#include <math.h>

#define B_ 8
#define N_ 2048
#define C_ 512
#define K_ 8
#define EPS 1e-6f
#define GENO_RATIO 0.1f

typedef __bf16 bf16x8 __attribute__((ext_vector_type(8)));
typedef float f32x4 __attribute__((ext_vector_type(4)));
typedef unsigned int u32;

__device__ __forceinline__ ushort f2bf(float x) {
    unsigned int u = __float_as_uint(x);
    u += 0x7fffu + ((u >> 16) & 1u);   // RNE (inputs are finite)
    return (ushort)(u >> 16);
}

__device__ __forceinline__ bf16x8 as_bf(uint4 x) {
    union { uint4 u; bf16x8 b; } t; t.u = x; return t.b;
}

// async global->LDS, 16B per lane. lds ptr must be wave-uniform (base+lane*16).
__device__ __forceinline__ void a_issue16(const ushort* g, ushort* l) {
    __builtin_amdgcn_global_load_lds(
        (const __attribute__((address_space(1))) u32*)g,
        (__attribute__((address_space(3))) u32*)l, 16, 0, 0);
}

// ---------------------------------------------------------------------------
// ws layout (float element offsets):
// [64,2112)            cnt (int)   [B,K] padded stride 32 (1 line/counter)
// [2112,4160)          mass        [B,K] padded stride 32
// [4160,36928)         hsum        [B,K,C]
// [36928,168000)       lw          [B,K,N]
// [168000,299072)      ln (int)    [B,K,N]
// [299072,1347648)     w1t2 (bf16) [K][16 cb][512 n][32 cc]   4 MB
// [1347648,5541952)    tb2  (bf16) [B][16 cb][2048 n][32 cc]  16.8 MB
// cnt/mass/hsum zeroed by hipMemsetAsync before k_prep.
// ---------------------------------------------------------------------------

// Gating blocks [0,1024): 4 waves x 4 tokens, gate weights in REGISTERS
// (lane owns 8 channels -> 16 float4 from L2-hot gate_w), geno bias folded
// per-(b,k) once per wave. No LDS, no barrier, no bank conflicts in gating.
// Blocks [1024,1536): w1 transpose+convert (unchanged).
__global__ __launch_bounds__(256) void k_prep(const float* __restrict__ tokens,
                                              const float* __restrict__ gate_w,
                                              const float* __restrict__ gate_b,
                                              const float* __restrict__ geno_vec,
                                              const float* __restrict__ geno_w,
                                              const float* __restrict__ geno_b,
                                              const float* __restrict__ w1,
                                              int* __restrict__ cnt,
                                              float* __restrict__ mass,
                                              int* __restrict__ ln,
                                              float* __restrict__ lw,
                                              ushort* __restrict__ tb2,
                                              ushort* __restrict__ w1t2) {
    __shared__ float smem[4160];   // transpose tile [64][65] only
    int tid = threadIdx.x;
    if (blockIdx.x < 1024) {
        int wave = tid >> 6, lane = tid & 63;
        int t0 = blockIdx.x * 16 + wave * 4;
        int b = t0 >> 11;               // 16-token runs never cross a batch
        int c0 = lane * 8;

        // gate weights for this lane's 8 channels, all 8 experts (64 VGPR)
        float4 gwlo[8], gwhi[8];
        const float* gwp = gate_w + (size_t)c0 * K_;
        #pragma unroll
        for (int m = 0; m < 8; ++m) {
            gwlo[m] = *(const float4*)(gwp + m * 8);
            gwhi[m] = *(const float4*)(gwp + m * 8 + 4);
        }

        // per-(b,k) bias incl. geno path, computed once per wave
        float gb[8];
        {
            const float* grow = geno_vec + (size_t)b * C_ + c0;
            float4 gy0 = *(const float4*)(grow);
            float4 gy1 = *(const float4*)(grow + 4);
            float gv[8] = {gy0.x, gy0.y, gy0.z, gy0.w, gy1.x, gy1.y, gy1.z, gy1.w};
            const float* qwp = geno_w + (size_t)c0 * K_;
            float gd[8] = {0.f, 0.f, 0.f, 0.f, 0.f, 0.f, 0.f, 0.f};
            #pragma unroll
            for (int m = 0; m < 8; ++m) {
                float4 qlo = *(const float4*)(qwp + m * 8);
                float4 qhi = *(const float4*)(qwp + m * 8 + 4);
                gd[0] = fmaf(gv[m], qlo.x, gd[0]);
                gd[1] = fmaf(gv[m], qlo.y, gd[1]);
                gd[2] = fmaf(gv[m], qlo.z, gd[2]);
                gd[3] = fmaf(gv[m], qlo.w, gd[3]);
                gd[4] = fmaf(gv[m], qhi.x, gd[4]);
                gd[5] = fmaf(gv[m], qhi.y, gd[5]);
                gd[6] = fmaf(gv[m], qhi.z, gd[6]);
                gd[7] = fmaf(gv[m], qhi.w, gd[7]);
            }
            #pragma unroll
            for (int off = 32; off > 0; off >>= 1) {
                #pragma unroll
                for (int j = 0; j < 8; ++j) gd[j] += __shfl_xor(gd[j], off, 64);
            }
            #pragma unroll
            for (int j = 0; j < 8; ++j)
                gb[j] = gate_b[j] + GENO_RATIO * (gd[j] + geno_b[j]);
        }

        const float* trow = tokens + (size_t)t0 * C_ + c0;
        #pragma unroll
        for (int tt = 0; tt < 4; ++tt) {
            int t = t0 + tt;
            int n = t & 2047;
            float4 v0 = *(const float4*)(trow + (size_t)tt * C_);
            float4 v1 = *(const float4*)(trow + (size_t)tt * C_ + 4);
            float tv[8] = {v0.x, v0.y, v0.z, v0.w, v1.x, v1.y, v1.z, v1.w};

            float acc[8];
            #pragma unroll
            for (int j = 0; j < 8; ++j) acc[j] = 0.f;
            #pragma unroll
            for (int m = 0; m < 8; ++m) {
                acc[0] = fmaf(tv[m], gwlo[m].x, acc[0]);
                acc[1] = fmaf(tv[m], gwlo[m].y, acc[1]);
                acc[2] = fmaf(tv[m], gwlo[m].z, acc[2]);
                acc[3] = fmaf(tv[m], gwlo[m].w, acc[3]);
                acc[4] = fmaf(tv[m], gwhi[m].x, acc[4]);
                acc[5] = fmaf(tv[m], gwhi[m].y, acc[5]);
                acc[6] = fmaf(tv[m], gwhi[m].z, acc[6]);
                acc[7] = fmaf(tv[m], gwhi[m].w, acc[7]);
            }
            {
                int cb = lane >> 2, cc = (lane & 3) * 8;
                uint4 o;
                o.x = (unsigned)f2bf(tv[0]) | ((unsigned)f2bf(tv[1]) << 16);
                o.y = (unsigned)f2bf(tv[2]) | ((unsigned)f2bf(tv[3]) << 16);
                o.z = (unsigned)f2bf(tv[4]) | ((unsigned)f2bf(tv[5]) << 16);
                o.w = (unsigned)f2bf(tv[6]) | ((unsigned)f2bf(tv[7]) << 16);
                *(uint4*)(tb2 + ((size_t)(b * 16 + cb) * 2048 + n) * 32 + cc) = o;
            }
            #pragma unroll
            for (int off = 32; off > 0; off >>= 1) {
                #pragma unroll
                for (int j = 0; j < 8; ++j) acc[j] += __shfl_xor(acc[j], off, 64);
            }
            if (lane == 0) {
                float lg[8];
                #pragma unroll
                for (int j = 0; j < 8; ++j) lg[j] = acc[j] + gb[j];
                int i0 = 0; float v0m = lg[0];
                #pragma unroll
                for (int j = 1; j < 8; ++j) if (lg[j] > v0m) { v0m = lg[j]; i0 = j; }
                int i1 = -1; float v1m = -1e30f;
                #pragma unroll
                for (int j = 0; j < 8; ++j) if (j != i0 && lg[j] > v1m) { v1m = lg[j]; i1 = j; }
                float e = expf(v1m - v0m);
                float w0 = 1.f / (1.f + e);
                float w1s = e / (1.f + e);
                w0 = fmaxf(w0, EPS); w1s = fmaxf(w1s, EPS);
                float s = w0 + w1s; w0 /= s; w1s /= s;
                int p0 = b * 8 + i0, p1 = b * 8 + i1;
                int pos0 = atomicAdd(cnt + (p0 << 5), 1);
                int pos1 = atomicAdd(cnt + (p1 << 5), 1);
                ln[p0 * N_ + pos0] = n;  lw[p0 * N_ + pos0] = w0;
                ln[p1 * N_ + pos1] = n;  lw[p1 * N_ + pos1] = w1s;
                atomicAdd(mass + (p0 << 5), w0);
                atomicAdd(mass + (p1 << 5), w1s);
            }
        }
    } else {
        // w1 transpose+convert: w1t2[k][cb][n][cc] = bf16(w1[k][cb*32+cc][n])
        int id2 = blockIdx.x - 1024;
        int k = id2 >> 6;
        int c0 = ((id2 >> 3) & 7) * 64;
        int n0 = (id2 & 7) * 64;
        float (*tile)[65] = (float(*)[65])smem;
        int tr = tid >> 4;          // 0..15
        int tc4 = (tid & 15) * 4;   // 0..60
        const float* src = w1 + (size_t)k * C_ * C_;
        #pragma unroll
        for (int i = 0; i < 4; ++i) {
            int c = c0 + tr + i * 16;
            float4 v = *(const float4*)(src + (size_t)c * C_ + n0 + tc4);
            tile[tr + i * 16][tc4 + 0] = v.x; tile[tr + i * 16][tc4 + 1] = v.y;
            tile[tr + i * 16][tc4 + 2] = v.z; tile[tr + i * 16][tc4 + 3] = v.w;
        }
        __syncthreads();
        #pragma unroll
        for (int i = 0; i < 4; ++i) {
            int rr = tr + i * 16;
            int n = n0 + rr;
            int c = c0 + tc4;
            int cb = c >> 5, cc = c & 31;
            uint2 o;
            o.x = (unsigned)f2bf(tile[tc4 + 0][rr]) | ((unsigned)f2bf(tile[tc4 + 1][rr]) << 16);
            o.y = (unsigned)f2bf(tile[tc4 + 2][rr]) | ((unsigned)f2bf(tile[tc4 + 3][rr]) << 16);
            *(uint2*)(w1t2 + ((size_t)(k * 16 + cb) * 512 + n) * 32 + cc) = o;
        }
    }
}

// grouped GEMM1, MFMA bf16. id = k + 8*b + 64*m  -> id&7 = k = XCD so each
// XCD keeps one expert's w1t2 (512 KB) hot in its private L2.
// Pipeline: A via global_load_lds into 3-slot LDS ring (2-deep), B 2-deep in
// VGPRs, raw s_barrier + counted s_waitcnt vmcnt(9) (never 0 in main loop).
__global__ __launch_bounds__(256, 2) void k_ffn1(const ushort* __restrict__ tb2,
                                                 const ushort* __restrict__ w1t2,
                                                 const float* __restrict__ b1,
                                                 const int* __restrict__ cnt,
                                                 const int* __restrict__ ln,
                                                 const float* __restrict__ lw,
                                                 float* __restrict__ hsum) {
    int id = blockIdx.x;
    int k = id & 7, b = (id >> 3) & 7, m = id >> 6;
    int p = b * 8 + k;
    int count = cnt[p << 5];
    int m0 = m * 64;
    if (m0 >= count) return;

    __shared__ __align__(16) ushort As[3][2048];   // 3 slots x 64 rows x 32 cc
    __shared__ int   ns_s[64];
    __shared__ float wls_s[64];
    int tid = threadIdx.x;
    if (tid < 64) {
        int mi = m0 + tid;
        bool v = mi < count;
        ns_s[tid]  = v ? ln[p * N_ + mi] : 0;
        wls_s[tid] = v ? lw[p * N_ + mi] : 0.f;
    }
    __syncthreads();

    int wv = tid >> 6, lane = tid & 63;
    int ln15 = lane & 15, q = lane >> 4;
    int r = tid >> 2, q4 = tid & 3;
    // gload_lds: wave-uniform LDS base (slot + wv*1024B); lane lands at +lane*16B
    // = byte tid*16 = row (tid>>2)*64 + piece (tid&3)*16 -> linear [64][32] tile.
    const ushort* ag = tb2 + ((size_t)(b * 16) * 2048 + ns_s[r]) * 32 + q4 * 8;
    const ushort* bb = w1t2 + ((size_t)(k * 16) * 512 + wv * 128 + ln15) * 32 + q * 8;

    f32x4 acc[4][8];
    #pragma unroll
    for (int mt = 0; mt < 4; ++mt)
        #pragma unroll
        for (int j = 0; j < 8; ++j) acc[mt][j] = (f32x4){0.f, 0.f, 0.f, 0.f};

    uint4 bA[8], bB[8];
    const ushort* s0 = &As[0][0];
    const ushort* s1 = &As[1][0];
    const ushort* s2 = &As[2][0];

    // prologue: issue stages 0 and 1 (9 VMEM ops each: 1 gload_lds + 8 b-loads)
    a_issue16(ag, (ushort*)s0 + wv * 512);
    #pragma unroll
    for (int j = 0; j < 8; ++j) bA[j] = *(const uint4*)(bb + j * 512);
    a_issue16(ag + 65536, (ushort*)s1 + wv * 512);
    #pragma unroll
    for (int j = 0; j < 8; ++j) bB[j] = *(const uint4*)(bb + 16384 + j * 512);

    #pragma unroll 1
    for (int cb = 0; cb < 14; cb += 2) {
        {   // body cb (even): read s0, consume bA, issue stage cb+2 -> s2/bA
            asm volatile("s_waitcnt vmcnt(9)" ::: "memory");
            __builtin_amdgcn_s_barrier();
            __builtin_amdgcn_sched_barrier(0);
            bf16x8 af[4];
            #pragma unroll
            for (int mt = 0; mt < 4; ++mt)
                af[mt] = *(const bf16x8*)(s0 + (mt * 16 + ln15) * 32 + q * 8);
            a_issue16(ag + (size_t)(cb + 2) * 65536, (ushort*)s2 + wv * 512);
            #pragma unroll
            for (int mt = 0; mt < 4; ++mt)
                #pragma unroll
                for (int j = 0; j < 8; ++j)
                    acc[mt][j] = __builtin_amdgcn_mfma_f32_16x16x32_bf16(
                        af[mt], as_bf(bA[j]), acc[mt][j], 0, 0, 0);
            #pragma unroll
            for (int j = 0; j < 8; ++j)
                bA[j] = *(const uint4*)(bb + (size_t)(cb + 2) * 16384 + j * 512);
        }
        {   // body cb+1 (odd): read s1, consume bB, issue stage cb+3 -> s0/bB
            asm volatile("s_waitcnt vmcnt(9)" ::: "memory");
            __builtin_amdgcn_s_barrier();
            __builtin_amdgcn_sched_barrier(0);
            bf16x8 af[4];
            #pragma unroll
            for (int mt = 0; mt < 4; ++mt)
                af[mt] = *(const bf16x8*)(s1 + (mt * 16 + ln15) * 32 + q * 8);
            a_issue16(ag + (size_t)(cb + 3) * 65536, (ushort*)s0 + wv * 512);
            #pragma unroll
            for (int mt = 0; mt < 4; ++mt)
                #pragma unroll
                for (int j = 0; j < 8; ++j)
                    acc[mt][j] = __builtin_amdgcn_mfma_f32_16x16x32_bf16(
                        af[mt], as_bf(bB[j]), acc[mt][j], 0, 0, 0);
            #pragma unroll
            for (int j = 0; j < 8; ++j)
                bB[j] = *(const uint4*)(bb + (size_t)(cb + 3) * 16384 + j * 512);
        }
        const ushort* t = s2; s2 = s1; s1 = s0; s0 = t;
    }
    {   // body 14: read s0 (slot 2), consume bA; A15/B15 (9 ops) stay in flight
        asm volatile("s_waitcnt vmcnt(9)" ::: "memory");
        __builtin_amdgcn_s_barrier();
        __builtin_amdgcn_sched_barrier(0);
        bf16x8 af[4];
        #pragma unroll
        for (int mt = 0; mt < 4; ++mt)
            af[mt] = *(const bf16x8*)(s0 + (mt * 16 + ln15) * 32 + q * 8);
        #pragma unroll
        for (int mt = 0; mt < 4; ++mt)
            #pragma unroll
            for (int j = 0; j < 8; ++j)
                acc[mt][j] = __builtin_amdgcn_mfma_f32_16x16x32_bf16(
                    af[mt], as_bf(bA[j]), acc[mt][j], 0, 0, 0);
    }
    {   // body 15: final drain
        asm volatile("s_waitcnt vmcnt(0)" ::: "memory");
        __builtin_amdgcn_s_barrier();
        __builtin_amdgcn_sched_barrier(0);
        bf16x8 af[4];
        #pragma unroll
        for (int mt = 0; mt < 4; ++mt)
            af[mt] = *(const bf16x8*)(s1 + (mt * 16 + ln15) * 32 + q * 8);
        #pragma unroll
        for (int mt = 0; mt < 4; ++mt)
            #pragma unroll
            for (int j = 0; j < 8; ++j)
                acc[mt][j] = __builtin_amdgcn_mfma_f32_16x16x32_bf16(
                    af[mt], as_bf(bB[j]), acc[mt][j], 0, 0, 0);
    }

    // epilogue: bias+relu+gate-weight; reduce 4 q-lanes; 1 atomic per column
    float wrow[4][4];
    #pragma unroll
    for (int mt = 0; mt < 4; ++mt)
        #pragma unroll
        for (int rr = 0; rr < 4; ++rr) wrow[mt][rr] = wls_s[mt * 16 + q * 4 + rr];
    const float* b1k = b1 + k * C_;
    float* hp = hsum + (size_t)p * C_;
    #pragma unroll
    for (int j = 0; j < 8; ++j) {
        int n = wv * 128 + j * 16 + ln15;
        float bias = b1k[n];
        float s = 0.f;
        #pragma unroll
        for (int mt = 0; mt < 4; ++mt)
            #pragma unroll
            for (int rr = 0; rr < 4; ++rr)
                s += wrow[mt][rr] * fmaxf(acc[mt][j][rr] + bias, 0.f);
        s += __shfl_xor(s, 16, 64);
        s += __shfl_xor(s, 32, 64);
        if (q == 0) atomicAdd(&hp[n], s);
    }
}

// fused combine+finalize: out[b,k,e] = (hsum[b,k,:]@w2[k,:,e] + b2*mass)/max(mass,eps)
// grid (et=8, k=8), 512 threads: 8 waves split c 8-ways (halved c-loop).
__global__ __launch_bounds__(512) void k_comb(const float* __restrict__ hsum,
                                              const float* __restrict__ w2,
                                              const float* __restrict__ b2,
                                              const float* __restrict__ mass,
                                              const int* __restrict__ cnt,
                                              float* __restrict__ out) {
    int et = blockIdx.x, k = blockIdx.y;
    int e0 = et * 64;
    __shared__ float hs[8][512];
    __shared__ float racc[8][8][64];
    int tid = threadIdx.x;
    for (int i = tid; i < 1024; i += 512) {
        int bb = i >> 7, c4 = (i & 127) << 2;
        *(float4*)&hs[bb][c4] = *(const float4*)(hsum + ((size_t)(bb * 8 + k) << 9) + c4);
    }
    __syncthreads();
    int g = tid >> 6, lane = tid & 63;
    const float* w2p = w2 + (size_t)k * (C_ * C_) + e0 + lane;
    float a[8] = {0.f, 0.f, 0.f, 0.f, 0.f, 0.f, 0.f, 0.f};
    #pragma unroll 4
    for (int c = g; c < 512; c += 8) {
        float wvv = w2p[(size_t)c << 9];
        #pragma unroll
        for (int bb = 0; bb < 8; ++bb) a[bb] = fmaf(hs[bb][c], wvv, a[bb]);
    }
    #pragma unroll
    for (int bb = 0; bb < 8; ++bb) racc[g][bb][lane] = a[bb];
    __syncthreads();
    {
        int bb = tid >> 6, le = tid & 63;
        float s = 0.f;
        #pragma unroll
        for (int gg = 0; gg < 8; ++gg) s += racc[gg][bb][le];
        float mm = mass[(bb * 8 + k) << 5];
        out[((size_t)(bb * 8 + k) << 9) + e0 + le] =
            (s + b2[k * C_ + e0 + le] * mm) / fmaxf(mm, EPS);
    }
    if (et == 0 && k == 0 && tid == 0) {
        float u[8]; float ssum = 0.f;
        for (int kk = 0; kk < 8; ++kk) {
            int ck = 0;
            for (int bb2 = 0; bb2 < 8; ++bb2) ck += cnt[(bb2 * 8 + kk) << 5];
            u[kk] = (float)ck / (float)(B_ * N_);
            ssum += u[kk];
        }
        float mean = ssum / 8.f;
        float var = 0.f;
        for (int kk = 0; kk < 8; ++kk) { float d = u[kk] - mean; var += d * d; }
        var /= 8.f;
        float denom = mean + EPS;
        out[B_ * K_ * C_] = var / (denom * denom);
    }
}

extern "C" void kernel_launch(void* const* d_in, const int* in_sizes, int n_in,
                              void* d_out, int out_size, void* d_ws, size_t ws_size,
                              hipStream_t stream) {
    (void)in_sizes; (void)n_in; (void)out_size; (void)ws_size;
    const float* tokens   = (const float*)d_in[0];
    const float* geno_vec = (const float*)d_in[1];
    const float* gate_w   = (const float*)d_in[2];
    const float* gate_b   = (const float*)d_in[3];
    const float* geno_w   = (const float*)d_in[4];
    const float* geno_b   = (const float*)d_in[5];
    const float* w1       = (const float*)d_in[6];
    const float* b1       = (const float*)d_in[7];
    const float* w2       = (const float*)d_in[8];
    const float* b2       = (const float*)d_in[9];
    float* out = (float*)d_out;
    float* ws  = (float*)d_ws;

    int*    cnt  = (int*)(ws + 64);            // padded [64][32]
    float*  mass = ws + 2112;                  // padded [64][32]
    float*  hsum = ws + 4160;                  // [64][512]
    float*  lw   = ws + 36928;                 // [64][2048]
    int*    ln   = (int*)(ws + 168000);        // [64][2048]
    ushort* w1t2 = (ushort*)(ws + 299072);     // 4 MB bf16
    ushort* tb2  = (ushort*)(ws + 1347648);    // 16.8 MB bf16

    hipMemsetAsync(ws + 64, 0, (size_t)(36928 - 64) * sizeof(float), stream);
    k_prep<<<dim3(1024 + 512), dim3(256), 0, stream>>>(tokens, gate_w, gate_b,
                                                       geno_vec, geno_w, geno_b,
                                                       w1, cnt, mass, ln, lw,
                                                       tb2, w1t2);
    k_ffn1<<<dim3(B_ * K_ * (N_ / 64)), dim3(256), 0, stream>>>(tb2, w1t2, b1,
                                                                cnt, ln, lw, hsum);
    k_comb<<<dim3(8, K_), dim3(512), 0, stream>>>(hsum, w2, b2, mass, cnt, out);
}